// Round 7
// baseline (197.011 us; speedup 1.0000x reference)
//
#include <hip/hip_runtime.h>
#include <hip/hip_bf16.h>

// BERT-CRF NER forward loss, MI355X.
//
// Linear-domain CRF: v_t = diag(E_t) * T * v_{t-1}, T = exp(transitions),
// E_t = exp(feats_t). NEG_INF -> exact 0. Associative => chunk the 511-step
// chain into 32 chunks of 16 steps; chunk products are 10x10 matrices,
// combined per batch in k2. Power-of-two renorm with exact integer scale
// bookkeeping keeps f32 in range.
//
//  k1 (grid 16x64, 128 thr = 2 waves, each wave owns one chunk):
//    stage: W (30KB) -> LDS cooperatively (kills the 10x broadcast-W
//           traffic through the vector-memory return path; LDS broadcast
//           reads are free per m136; ~4cy/instr return -> ~6.4us/CU,
//           overlapped under the ~16us HBM window).
//    A: feats rows t=c*16+1..+16: row-per-lane&15, K-quarter lane>>4
//       interleaved (float4 index j*4+q -> contiguous 64B wave segments);
//       shfl_xor reduce; E=exp2(feat*log2e) -> LDS; gold partial -> golds.
//    B: barrier-free per-wave chunk product: lane ep=lane%10 owns column
//       ep of P, full T (100 f32) in VGPRs; per step one LDS broadcast
//       row read of E. Renorm every 4 steps (growth <= 2^72 << 2^127).
//  k2 (grid 64, 64 thr): stage the batch's 32 chunk matrices (12.8 KB) into
//    LDS via 50 coalesced parallel loads, then 31 matvecs out of LDS with a
//    2-deep register pipeline; loss = ln2*(log2(sum v)+C) - gold; atomic
//    mean into memset-zeroed d_out.
//
// Budget (paper): k1 HBM-bound ~17-21us (hidden = 100.7MB read once; VALU
// ~4us/SIMD; LDS ~6.4us/CU; VMEM instr/wave 63); k2 ~2-3us. Renorm max
// clamped at 1e-33 as FTZ insurance (m>0 provable). Design held steady —
// paper-saturated; next branch decided by first real counter run.

#define NL 10
#define TL 512
#define HDIM 768
#define CS 16
#define NCHUNK 32
#define LOG2E_F 1.4426950408889634f
#define LN2_F 0.6931471805599453f

__global__ __launch_bounds__(128, 2) void crf_chunk(
    const float* __restrict__ hidden, const float* __restrict__ W,
    const float* __restrict__ bias, const float* __restrict__ trans,
    const int* __restrict__ labels, float* __restrict__ Pmats,
    float* __restrict__ Cc, float* __restrict__ golds)
{
  const int tid = threadIdx.x;
  const int w = tid >> 6;              // wave id 0/1
  const int lane = tid & 63;
  const int c = blockIdx.x * 2 + w;    // chunk owned by this wave
  const int b = blockIdx.y;            // batch
  const int r = lane & 15;             // row within chunk
  const int q = lane >> 4;             // K-quarter (interleaved)
  const int t = c * CS + 1 + r;        // global time step (t=0 feeds nothing)
  const bool valid = (t < TL);
  const int tc = valid ? t : (TL - 1);

  __shared__ float4 sW[1920];          // 30 KB: full W as float4[l*192 + j4]
  __shared__ float sE[2][CS][12];      // per-wave exp(feats) rows, 48 B pitch

  // ---- cooperative W stage: 1920 float4, 15 per thread, coalesced ----
#pragma unroll
  for (int i = 0; i < 15; ++i) {
    const int idx = i * 128 + tid;
    sW[idx] = ((const float4*)W)[idx];
  }
  __syncthreads();

  // ---------------- phase A: GEMM 16 rows x 768 -> 10 ----------------
  float acc[NL];
#pragma unroll
  for (int l = 0; l < NL; ++l) acc[l] = 0.0f;

  // float4 chunk index j*4+q: the 4 q-groups read CONSECUTIVE float4s, so
  // a 16-lane row-group + its q-neighbors form contiguous 64B segments.
  const float4* __restrict__ h4 =
      (const float4*)(hidden + ((size_t)b * TL + tc) * HDIM) + q;
#pragma unroll 8
  for (int j = 0; j < 48; ++j) {
    const float4 h = h4[j * 4];
#pragma unroll
    for (int l = 0; l < NL; ++l) {
      const float4 wv = sW[l * 192 + j * 4 + q];  // 16-lane broadcast read
      acc[l] += h.x * wv.x + h.y * wv.y + h.z * wv.z + h.w * wv.w;
    }
  }
#pragma unroll
  for (int l = 0; l < NL; ++l) {   // reduce the 4 K-quarters
    acc[l] += __shfl_xor(acc[l], 16);
    acc[l] += __shfl_xor(acc[l], 32);
    acc[l] += bias[l];
  }

  float g = 0.0f;
  if (lane < CS) {  // q==0 lanes own the 16 rows
#pragma unroll
    for (int l = 0; l < NL; ++l)
      sE[w][r][l] = valid ? exp2f(acc[l] * LOG2E_F) : 0.0f;
    if (valid) {
      const int cu = labels[b * TL + t];
      const int pv = labels[b * TL + t - 1];  // t-1 at r=0 is not wave-local:
      float emit = 0.0f;                      // two loads are required
#pragma unroll
      for (int l = 0; l < NL; ++l) emit = (cu == l) ? acc[l] : emit;
      g = emit + trans[cu * NL + pv];
    }
  }
#pragma unroll
  for (int off = 32; off; off >>= 1) g += __shfl_down(g, off);
  if (lane == 0) golds[b * NCHUNK + c] = g;

  __syncthreads();  // sE[w] visible to own wave (cheap; also orders sW reuse)

  // ------------- phase B: barrier-free 10x10 chain product -------------
  const int ep = lane % NL;  // column owned (lanes >=10 duplicate: no divergence)

  float Tm[NL][NL];  // T = exp(transitions); NEG_INF row/col -> exact 0
#pragma unroll
  for (int el = 0; el < NL; ++el)
#pragma unroll
    for (int k = 0; k < NL; ++k)
      Tm[el][k] = exp2f(trans[el * NL + k] * LOG2E_F);

  float p[NL];  // column ep of running product P
#pragma unroll
  for (int el = 0; el < NL; ++el) p[el] = sE[w][0][el] * Tm[el][ep];

  const int NT = (c == NCHUNK - 1) ? (CS - 1) : CS;  // 511 = 31*16 + 15
  float Cacc = 0.0f;  // integer-valued log2 scale, exact in f32

  for (int s = 1; s < NT; ++s) {
    const float* __restrict__ se = &sE[w][s][0];  // uniform addr: broadcast
    float pn[NL];
#pragma unroll
    for (int el = 0; el < NL; ++el) {
      float sum = Tm[el][0] * p[0];
#pragma unroll
      for (int k = 1; k < NL; ++k) sum += Tm[el][k] * p[k];
      pn[el] = se[el] * sum;
    }
#pragma unroll
    for (int el = 0; el < NL; ++el) p[el] = pn[el];

    if ((s & 3) == 3 || s == NT - 1) {  // wave-uniform renorm, exact pow-2
      float m = p[0];
#pragma unroll
      for (int el = 1; el < NL; ++el) m = fmaxf(m, p[el]);
#pragma unroll
      for (int off = 1; off < 64; off <<= 1) m = fmaxf(m, __shfl_xor(m, off));
      m = fmaxf(m, 1e-33f);                  // FTZ insurance; m>0 provable
      const float e = floorf(log2f(m));
      const float scl = exp2f(-e);
      Cacc += e;
#pragma unroll
      for (int el = 0; el < NL; ++el) p[el] *= scl;
    }
  }

  float* __restrict__ Pb = Pmats + (size_t)(b * NCHUNK + c) * 100;
  if (lane < NL) {
#pragma unroll
    for (int el = 0; el < NL; ++el) Pb[el * NL + ep] = p[el];  // row-major
  }
  if (lane == 0) Cc[b * NCHUNK + c] = Cacc;
}

__global__ __launch_bounds__(64, 2) void crf_combine(
    const float* __restrict__ Pmats, const float* __restrict__ Cc,
    const float* __restrict__ golds, float* __restrict__ out)
{
  const int b = blockIdx.x;
  const int lane = threadIdx.x;
  const int el = lane % NL;  // row owned (duplicated across lanes >= 10)

  __shared__ float sP[NCHUNK * 100];  // 12.8 KB: this batch's chunk matrices

  // Bulk coalesced stage: 50 independent wave-wide loads, one wait.
  const float* __restrict__ src = Pmats + (size_t)b * (NCHUNK * 100);
#pragma unroll
  for (int i = 0; i < (NCHUNK * 100) / 64; ++i)
    sP[i * 64 + lane] = src[i * 64 + lane];

  // Reduce scale/gold partials while the stage loads are in flight.
  float cg = (lane < NCHUNK) ? Cc[b * NCHUNK + lane] : 0.0f;
  float gg = (lane < NCHUNK) ? golds[b * NCHUNK + lane] : 0.0f;
#pragma unroll
  for (int off = 16; off; off >>= 1) {
    cg += __shfl_down(cg, off);
    gg += __shfl_down(gg, off);
  }
  float C = __shfl(cg, 0);
  const float gold = __shfl(gg, 0);

  __syncthreads();

  // v0 = e_START (START=1) => v after chunk 0 is just column 1 of P_0.
  // v is replicated across all lanes (broadcast LDS reads).
  float v[NL];
#pragma unroll
  for (int p = 0; p < NL; ++p) v[p] = sP[p * NL + 1];

  // 2-deep register pipeline over chunks 1..31 (static reg indices only).
  float bufA[NL], bufB[NL];
#pragma unroll
  for (int k = 0; k < NL; ++k) bufA[k] = sP[1 * 100 + el * NL + k];

  for (int c = 1; c < NCHUNK; c += 2) {
    const int cn = (c + 1 < NCHUNK) ? (c + 1) : c;  // clamped prefetch
#pragma unroll
    for (int k = 0; k < NL; ++k) bufB[k] = sP[cn * 100 + el * NL + k];

    // consume chunk c (bufA)
    float nv = bufA[0] * v[0];
#pragma unroll
    for (int k = 1; k < NL; ++k) nv += bufA[k] * v[k];
#pragma unroll
    for (int p = 0; p < NL; ++p) v[p] = __shfl(nv, p);

    if (c + 1 < NCHUNK) {
      const int cn2 = (c + 2 < NCHUNK) ? (c + 2) : (c + 1);
#pragma unroll
      for (int k = 0; k < NL; ++k) bufA[k] = sP[cn2 * 100 + el * NL + k];

      // consume chunk c+1 (bufB)
      float nv2 = bufB[0] * v[0];
#pragma unroll
      for (int k = 1; k < NL; ++k) nv2 += bufB[k] * v[k];
#pragma unroll
      for (int p = 0; p < NL; ++p) v[p] = __shfl(nv2, p);

      // renorm every 2 chunks (growth <= ~400x per pair: ample margin);
      // v replicated => pure per-lane work, no cross-lane reduce.
      float m = v[0];
#pragma unroll
      for (int p = 1; p < NL; ++p) m = fmaxf(m, v[p]);
      m = fmaxf(m, 1e-33f);                  // FTZ insurance
      const float e = floorf(log2f(m));
      const float scl = exp2f(-e);
      C += e;
#pragma unroll
      for (int p = 0; p < NL; ++p) v[p] *= scl;
    }
  }

  float s = 0.0f;
#pragma unroll
  for (int p = 0; p < NL; ++p) s += v[p];
  const float fwd = LN2_F * (log2f(s) + C);
  if (lane == 0) atomicAdd(out, (fwd - gold) * (1.0f / 64.0f));
}

extern "C" void kernel_launch(void* const* d_in, const int* in_sizes, int n_in,
                              void* d_out, int out_size, void* d_ws, size_t ws_size,
                              hipStream_t stream) {
  const float* hidden = (const float*)d_in[0];
  const float* W      = (const float*)d_in[1];
  const float* bias   = (const float*)d_in[2];
  const float* trans  = (const float*)d_in[3];
  const int*   labels = (const int*)d_in[4];

  float* ws    = (float*)d_ws;
  float* Pmats = ws;                        // 64*32*100
  float* Cc    = ws + 64 * NCHUNK * 100;    // 64*32
  float* golds = Cc + 64 * NCHUNK;          // 64*32

  hipMemsetAsync(d_out, 0, sizeof(float), stream);

  dim3 grid1(NCHUNK / 2, 64);
  crf_chunk<<<grid1, 128, 0, stream>>>(hidden, W, bias, trans, labels,
                                       Pmats, Cc, golds);
  crf_combine<<<64, 64, 0, stream>>>(Pmats, Cc, golds, (float*)d_out);
}